// Round 19
// baseline (171.872 us; speedup 1.0000x reference)
//
#include <hip/hip_runtime.h>
#include <hip/hip_bf16.h>

// ============================================================================
// Round 19: one-variable experiment — conv4 occupancy 3 -> 5 blocks/CU.
// R18 confirmed NT stores fixed write amplification (WRITE exactly 64MiB,
// FETCH 7MB) and conv4 is now latency-limited (MfmaUtil 30%, HBM 28%, occ 28%
// at 3 blk/CU). NT stores are immune to the r16 dirty-window thrash (no
// allocate / no dirty L2 lines), so the r16 occupancy penalty should not
// recur. If WRITE balloons again, the NT model is wrong -> revert.
// Everything else byte-identical to r18 (absmax 7.629395e-6).
// ============================================================================

typedef __attribute__((ext_vector_type(8))) short short8;
typedef __attribute__((ext_vector_type(4))) float f32x4;

// ---- workspace layout (bytes) ----
static const size_t OFF_A1H = 0;                       // A1/A4 NHWC hi (B,34,34,64) 9.25MB
static const size_t OFF_PL  = 18939904;                // pooled (64,64,16,16) f32 4MB
static const size_t OFF_A3H = 39911424;                // conv3 input NHWC hi (B,18,18,64)
static const size_t OFF_W1  = 45219840;                // packed whi+wlo 147,456 B/layer
static const size_t OFF_W3  = 45367296;
static const size_t OFF_W4  = 45514752;
static const size_t OFF_RS  = 45662208;                // rs_part (24,256) f64 49,152B
static const size_t OFF_XE  = 45711360;                // xE (64,256) f32 64KB
static const size_t OFF_Z   = 45776896;                // zE (64,768) f32 192KB
static const size_t OFF_GW  = 45973504;                // gwT (3,256) f32 3KB -> ~46MB

__device__ inline void bf16split(float v, unsigned short& h, unsigned short& l) {
    __hip_bfloat16 hb = __float2bfloat16(v);
    float hf = __bfloat162float(hb);
    __hip_bfloat16 lb = __float2bfloat16(v - hf);
    h = __builtin_bit_cast(unsigned short, hb);
    l = __builtin_bit_cast(unsigned short, lb);
}

__device__ inline unsigned short bf16of(float v) {
    __hip_bfloat16 hb = __float2bfloat16(v);
    return __builtin_bit_cast(unsigned short, hb);
}

// ---- prep: wpack (0..431) + rowsum partials (432..455) + gammaW (456) ----
__global__ void wprep_rowsum_kernel(
    const float* __restrict__ w1, const float* __restrict__ w3,
    const float* __restrict__ w4, const float* __restrict__ w_out,
    const float* __restrict__ w_param,
    unsigned short* __restrict__ whi1, unsigned short* __restrict__ wlo1,
    unsigned short* __restrict__ whi3, unsigned short* __restrict__ wlo3,
    unsigned short* __restrict__ whi4, unsigned short* __restrict__ wlo4,
    double* __restrict__ rsP, float* __restrict__ gwT)
{
    int blk = blockIdx.x;
    if (blk == 456) {                                  // gammaW column gather
        int t = threadIdx.x;
#pragma unroll
        for (int r = 0; r < 3; ++r)
            gwT[r * 256 + t] = w_param[(size_t)t * 3108 + r * 262 + 261];
        return;
    }
    if (blk >= 432) {                                  // rowsum partials
        int idx = blk - 432;                           // 0..23
        int r = idx >> 3, c = idx & 7;
        int m = threadIdx.x;
        const float* wp = w_out + (size_t)(256 + r * 256 + c * 32) * 256 + m;
        double s[4] = {0, 0, 0, 0};
        for (int d0 = 0; d0 < 32; d0 += 4) {
#pragma unroll
            for (int k = 0; k < 4; ++k)
                s[k] += (double)wp[(size_t)(d0 + k) * 256];
        }
        rsP[(idx << 8) + m] = (s[0] + s[1]) + (s[2] + s[3]);
        return;
    }
    int layer = blk / 144;
    int r = (blk % 144) * 256 + threadIdx.x;           // < 36864
    const float* w = layer == 0 ? w1 : (layer == 1 ? w3 : w4);
    unsigned short* hi = layer == 0 ? whi1 : (layer == 1 ? whi3 : whi4);
    unsigned short* lo = layer == 0 ? wlo1 : (layer == 1 ? wlo3 : wlo4);
    int j  = r & 7;
    int ln = (r >> 3) & 63;
    int n  = (r >> 9) & 3;
    int ch = (r >> 11) & 1;
    int t  = r >> 12;
    int lc = ln & 15, kg = ln >> 4;
    int co = n * 16 + lc;
    int ci = ch * 32 + kg * 8 + j;
    unsigned short h, l;
    bf16split(w[(co * 64 + ci) * 9 + t], h, l);
    hi[r] = h; lo[r] = l;
}

// ---- zero halo rings of a1h (S=32) and a3h (S=16) ----
__device__ inline void halo_zero_one(unsigned short* hi, int S, int idx)
{
    int P = S + 2, ring = 4 * S + 4;
    int co = idx & 63;
    int cell = (idx >> 6) % ring;
    int b = (idx >> 6) / ring;
    int y, x;
    if (cell < P)            { y = 0;     x = cell; }
    else if (cell < 2 * P)   { y = P - 1; x = cell - P; }
    else { int c2 = cell - 2 * P; y = 1 + (c2 >> 1); x = (c2 & 1) ? P - 1 : 0; }
    hi[((size_t)(b * P + y) * P + x) * 64 + co] = 0;
}

__global__ void halo_all_kernel(unsigned short* __restrict__ a1h,
                                unsigned short* __restrict__ a3h)
{
    int idx = blockIdx.x * 256 + threadIdx.x;          // 819,200 total
    if (idx < 540672) halo_zero_one(a1h, 32, idx);
    else              halo_zero_one(a3h, 16, idx - 540672);
}

// ---- fused conv0 (1->64, 3x3 SAME, relu) + avgpool2 -> A1 NHWC bf16 ----
__global__ __launch_bounds__(256) void conv0_pool_kernel(
    const float* __restrict__ in, const float* __restrict__ w,
    const float* __restrict__ bias, unsigned short* __restrict__ ohi)
{
    int idx = blockIdx.x * 256 + threadIdx.x;          // 4,194,304
    int co = idx & 63, x = (idx >> 6) & 31, y = (idx >> 11) & 31, b = idx >> 16;
    float w9[9];
#pragma unroll
    for (int t = 0; t < 9; ++t) w9[t] = w[co * 9 + t];
    float bv = bias[co];
    const float* ip = in + (size_t)b * 4096;
    float p[4][4];
#pragma unroll
    for (int r = 0; r < 4; ++r) {
        int gy = 2 * y - 1 + r;
#pragma unroll
        for (int c = 0; c < 4; ++c) {
            int gx = 2 * x - 1 + c;
            float v = 0.f;
            if ((unsigned)gy < 64u && (unsigned)gx < 64u) v = ip[gy * 64 + gx];
            p[r][c] = v;
        }
    }
    float s4 = 0.f;
#pragma unroll
    for (int dy = 0; dy < 2; ++dy)
#pragma unroll
        for (int dx = 0; dx < 2; ++dx) {
            float a = bv;
#pragma unroll
            for (int ky = 0; ky < 3; ++ky)
#pragma unroll
                for (int kx = 0; kx < 3; ++kx)
                    a = fmaf(w9[ky * 3 + kx], p[dy + ky][dx + kx], a);
            s4 += fmaxf(a, 0.f);
        }
    size_t a = ((size_t)(b * 34 + y + 1) * 34 + x + 1) * 64 + co;
    ohi[a] = bf16of(s4 * 0.25f);
}

// ---- MFMA implicit-GEMM conv body: 2-pass (ah*bh + ah*bl), A hi-only ----
// XT = x-tiles per wave. OUTMODE: 0 = NCHW f32 (nontemporal, final output),
// 1 = NHWC bf16 hi, 2 = fused relu+avgpool2 (ROWS==2).
template <int UP, int H, int ROWS, int XT, int OUTMODE>
__device__ __forceinline__ void conv_mfma_body(
    const unsigned short* __restrict__ ahi,
    const unsigned short* __restrict__ whiP, const unsigned short* __restrict__ wloP,
    const float* __restrict__ bias,
    float* __restrict__ outf, unsigned short* __restrict__ ohi)
{
    constexpr int TILEH = 4 * ROWS;
    constexpr int TILEW = 16 * XT;
    constexpr int SRC   = H >> UP;
    constexpr int PITCH = SRC + 2;
    constexpr int TPR   = H / TILEW;
    constexpr int TPC   = H / TILEH;
    constexpr int AH    = (UP ? TILEH / 2 : TILEH) + 2;
    constexpr int AW    = (UP ? TILEW / 2 : TILEW) + 2;
    constexpr int NPX   = AH * AW;

    int b  = blockIdx.x / (TPC * TPR);
    int tt = blockIdx.x % (TPC * TPR);
    int y0 = (tt / TPR) * TILEH, x0 = (tt % TPR) * TILEW;
    const int tid = threadIdx.x;
    const int wv = tid >> 6, lane = tid & 63;
    const int lc = lane & 15, kg = lane >> 4;

    __shared__ unsigned short sAhi[NPX * 64];
    __shared__ unsigned short sW[2][4096];             // [buf][hi 2048 | lo 2048]

    const int r0 = ((y0 - 1) >> UP) + 1;
    const int c0 = ((x0 - 1) >> UP) + 1;

    for (int c = tid; c < NPX * 8; c += 256) {
        int pix = c >> 3, sub = c & 7;
        int py = pix / AW, px = pix - py * AW;
        size_t g = ((size_t)(b * PITCH + r0 + py) * PITCH + (c0 + px)) * 64 + sub * 8;
        int l = (pix * 64 + sub * 8) ^ ((pix & 7) << 3);
        *(short8*)&sAhi[l] = *(const short8*)&ahi[g];
    }
    for (int c = tid; c < 512; c += 256) {
        if (c < 256) *(short8*)&sW[0][c * 8] = *(const short8*)&whiP[c * 8];
        else *(short8*)&sW[0][2048 + (c - 256) * 8] = *(const short8*)&wloP[(c - 256) * 8];
    }
    __syncthreads();

    int lxv[3][XT], lyv[ROWS + 2];
#pragma unroll
    for (int kx = 0; kx < 3; ++kx)
#pragma unroll
        for (int xt = 0; xt < XT; ++xt)
            lxv[kx][xt] = (((x0 + xt * 16 + lc + kx - 1) >> UP) + 1) - c0;
#pragma unroll
    for (int r = 0; r < ROWS + 2; ++r)
        lyv[r] = (((y0 + ROWS * wv + r - 1) >> UP) + 1) - r0;

    f32x4 acc[ROWS][XT][4];
#pragma unroll
    for (int m = 0; m < ROWS; ++m)
#pragma unroll
        for (int xt = 0; xt < XT; ++xt)
#pragma unroll
            for (int n = 0; n < 4; ++n) acc[m][xt][n] = f32x4{0.f, 0.f, 0.f, 0.f};

#pragma unroll
    for (int k = 0; k < 18; ++k) {                     // k = t*2 + ch
        if (k + 1 < 18) {                              // prefetch next W slice
            int slb = (k + 1) * 2048;
            for (int c = tid; c < 512; c += 256) {
                if (c < 256) *(short8*)&sW[(k + 1) & 1][c * 8] =
                    *(const short8*)&whiP[slb + c * 8];
                else *(short8*)&sW[(k + 1) & 1][2048 + (c - 256) * 8] =
                    *(const short8*)&wloP[slb + (c - 256) * 8];
            }
        }
        const int t = k >> 1, ch = k & 1;
        const int ky = t / 3, kx = t - ky * 3;
        short8 ah[ROWS][XT];
#pragma unroll
        for (int m = 0; m < ROWS; ++m)
#pragma unroll
            for (int xt = 0; xt < XT; ++xt) {
                int p = lyv[ky + m] * AW + lxv[kx][xt];
                int i = (p * 64 + ch * 32 + kg * 8) ^ ((p & 7) << 3);
                ah[m][xt] = *(const short8*)&sAhi[i];
            }
        const unsigned short* wb = &sW[k & 1][0];
#pragma unroll
        for (int n = 0; n < 4; ++n) {
            short8 bh = *(const short8*)&wb[(n * 64 + lane) * 8];
            short8 bl = *(const short8*)&wb[2048 + (n * 64 + lane) * 8];
#pragma unroll
            for (int xt = 0; xt < XT; ++xt)
#pragma unroll
                for (int m = 0; m < ROWS; ++m) {
                    acc[m][xt][n] = __builtin_amdgcn_mfma_f32_16x16x32_bf16(ah[m][xt], bh, acc[m][xt][n], 0, 0, 0);
                    acc[m][xt][n] = __builtin_amdgcn_mfma_f32_16x16x32_bf16(ah[m][xt], bl, acc[m][xt][n], 0, 0, 0);
                }
        }
        __syncthreads();
    }

    // epilogue: D col(lane&15)=co frag idx, row(kg*4+reg)=pixel-x (verified r4)
    if (OUTMODE == 1) {
        const int opitch = H + 2;
#pragma unroll
        for (int n = 0; n < 4; ++n) {
            int co = n * 16 + lc;
            float bv = bias[co];
#pragma unroll
            for (int m = 0; m < ROWS; ++m)
#pragma unroll
                for (int xt = 0; xt < XT; ++xt) {
                    int row = y0 + ROWS * wv + m, cb = x0 + xt * 16 + kg * 4;
                    f32x4 v = acc[m][xt][n];
#pragma unroll
                    for (int j = 0; j < 4; ++j) {
                        float val = fmaxf(v[j] + bv, 0.f);
                        size_t a = ((size_t)(b * opitch + row + 1) * opitch + cb + j + 1) * 64 + co;
                        ohi[a] = bf16of(val);
                    }
                }
        }
    } else if (OUTMODE == 2) {                         // fused relu+avgpool2 (ROWS==2)
#pragma unroll
        for (int n = 0; n < 4; ++n) {
            int co = n * 16 + lc;
            float bv = bias[co];
#pragma unroll
            for (int xt = 0; xt < XT; ++xt) {
                f32x4 v0 = acc[0][xt][n], v1 = acc[1][xt][n];
                float r00 = fmaxf(v0.x + bv, 0.f), r01 = fmaxf(v0.y + bv, 0.f);
                float r02 = fmaxf(v0.z + bv, 0.f), r03 = fmaxf(v0.w + bv, 0.f);
                float r10 = fmaxf(v1.x + bv, 0.f), r11 = fmaxf(v1.y + bv, 0.f);
                float r12 = fmaxf(v1.z + bv, 0.f), r13 = fmaxf(v1.w + bv, 0.f);
                float p0 = ((r00 + r01) + (r10 + r11)) * 0.25f;
                float p1 = ((r02 + r03) + (r12 + r13)) * 0.25f;
                int py = (y0 >> 1) + wv;
                int px = ((x0 + xt * 16) >> 1) + kg * 2;
                float* op = outf + ((size_t)(b * 64 + co) * 16 + py) * 16 + px;
                op[0] = p0; op[1] = p1;
            }
        }
    } else {                                           // final output: stream past L2
#pragma unroll
        for (int n = 0; n < 4; ++n) {
            int co = n * 16 + lc;
            float bv = bias[co];
#pragma unroll
            for (int m = 0; m < ROWS; ++m)
#pragma unroll
                for (int xt = 0; xt < XT; ++xt) {
                    int row = y0 + ROWS * wv + m, cb = x0 + xt * 16 + kg * 4;
                    f32x4 v = acc[m][xt][n], res;
                    res.x = fmaxf(v.x + bv, 0.f);
                    res.y = fmaxf(v.y + bv, 0.f);
                    res.z = fmaxf(v.z + bv, 0.f);
                    res.w = fmaxf(v.w + bv, 0.f);
                    __builtin_nontemporal_store(res,
                        (f32x4*)&outf[((size_t)(b * 64 + co) * H + row) * H + cb]);
                }
        }
    }
}

__global__ __launch_bounds__(256, 4) void conv1_mfma_kernel(
    const unsigned short* __restrict__ ahi,
    const unsigned short* __restrict__ whiP, const unsigned short* __restrict__ wloP,
    const float* __restrict__ bias, float* __restrict__ pooled)
{ conv_mfma_body<0, 32, 2, 1, 2>(ahi, whiP, wloP, bias, pooled, nullptr); }

__global__ __launch_bounds__(256, 6) void conv3_mfma_kernel(
    const unsigned short* __restrict__ ahi,
    const unsigned short* __restrict__ whiP, const unsigned short* __restrict__ wloP,
    const float* __restrict__ bias, unsigned short* __restrict__ ohi)
{ conv_mfma_body<1, 32, 2, 1, 1>(ahi, whiP, wloP, bias, nullptr, ohi); }

// conv4: r15 geometry (16x16 tile, ROWS=4) + NT stores, occupancy 3 -> 5
__global__ __launch_bounds__(256, 5) void conv4_mfma_kernel(
    const unsigned short* __restrict__ ahi,
    const unsigned short* __restrict__ whiP, const unsigned short* __restrict__ wloP,
    const float* __restrict__ bias, float* __restrict__ outf)
{ conv_mfma_body<1, 64, 4, 1, 0>(ahi, whiP, wloP, bias, outf, nullptr); }

// ---- enc: pooled (b,64,16,16) -> xE (64,256) ----
__global__ __launch_bounds__(1024) void enc_kernel(
    const float* __restrict__ pooled, const float* __restrict__ w_enc,
    const float* __restrict__ b_enc, float* __restrict__ xE)
{
    int b = blockIdx.x, t = threadIdx.x;
    __shared__ float sE[16384];
    __shared__ float eP[4][256];
    {
        const f32x4* src = (const f32x4*)(pooled + (size_t)b * 16384);
        f32x4* dst = (f32x4*)sE;
#pragma unroll
        for (int p = t; p < 4096; p += 1024) dst[p] = src[p];
    }
    __syncthreads();
    {
        int g = t >> 8, j = t & 255;
        int y = j >> 4, x = j & 15;
        float a0 = 0.f, a1 = 0.f;
        for (int cc = 0; cc < 16; ++cc) {
            int ci = g * 16 + cc;
#pragma unroll
            for (int ky = 0; ky < 3; ++ky) {
                int gy = y + ky - 1;
                if ((unsigned)gy >= 16u) continue;
#pragma unroll
                for (int kx = 0; kx < 3; ++kx) {
                    int gx = x + kx - 1;
                    if ((unsigned)gx >= 16u) continue;
                    float pr = w_enc[ci * 9 + ky * 3 + kx] * sE[ci * 256 + gy * 16 + gx];
                    if (cc & 1) a1 += pr; else a0 += pr;
                }
            }
        }
        eP[g][j] = a0 + a1;
    }
    __syncthreads();
    if (t < 256) {
        float v = ((eP[0][t] + eP[1][t]) + (eP[2][t] + eP[3][t])) + b_enc[0];
        xE[b * 256 + t] = fmaxf(v, 0.f);
    }
}

// ---- lstm z-GEMM: 192 blocks = (gate g, image b); thread = column j ----
__global__ __launch_bounds__(256) void lstm_kernel(
    const float* __restrict__ xE, const float* __restrict__ wx,
    float* __restrict__ zE)
{
    int blk = blockIdx.x;
    int g = blk >> 6, b = blk & 63;
    int goff = (g == 0) ? 0 : (g == 1 ? 512 : 768);
    int j = threadIdx.x;
    __shared__ float sx[256];
    sx[j] = xE[b * 256 + j];
    __syncthreads();
    const float* wp = wx + goff + j;
    float acc[8];
#pragma unroll
    for (int k = 0; k < 8; ++k) acc[k] = 0.f;
    for (int d0 = 0; d0 < 256; d0 += 8) {
        float xv[8], wv[8];
#pragma unroll
        for (int k = 0; k < 8; ++k) xv[k] = sx[d0 + k];
#pragma unroll
        for (int k = 0; k < 8; ++k) wv[k] = wp[(size_t)(d0 + k) * 1024];
#pragma unroll
        for (int k = 0; k < 8; ++k) acc[k] = fmaf(xv[k], wv[k], acc[k]);
    }
    zE[b * 768 + g * 256 + j] = ((acc[0] + acc[1]) + (acc[2] + acc[3]))
                              + ((acc[4] + acc[5]) + (acc[6] + acc[7]));
}

// ---- tail: gates + gamma + ntmout + conv2 -> A3 NHWC bf16 (block = image) ----
__global__ __launch_bounds__(1024) void tail_kernel(
    const float* __restrict__ zE, const float* __restrict__ bl,
    const float* __restrict__ gwT, const float* __restrict__ b_param,
    const float* __restrict__ w_out, const float* __restrict__ b_out,
    const double* __restrict__ rsP, const float* __restrict__ w2,
    const float* __restrict__ b2, unsigned short* __restrict__ ohi)
{
    int b = blockIdx.x, t = threadIdx.x;
    __shared__ float  sh[256];
    __shared__ double red[3][256];
    __shared__ double srv[3];
    __shared__ float  dP[4][256];
    __shared__ float  sNtm[256];

    if (t < 256) {                                     // gates (fp64 math)
        int j = t;
        float zif = (float)((double)zE[b * 768 + j]       + (double)bl[j]);
        float zgf = (float)((double)zE[b * 768 + 256 + j] + (double)bl[512 + j]);
        float zof = (float)((double)zE[b * 768 + 512 + j] + (double)bl[768 + j]);
        double c = (1.0 / (1.0 + exp(-(double)zif))) * tanh((double)zgf);
        float cf = (float)c;
        double hh = (1.0 / (1.0 + exp(-(double)zof))) * tanh((double)cf);
        sh[j] = (float)hh;
    }
    __syncthreads();
    // gamma: products (contiguous gwT) then LDS tree reduce
    if (t < 768) {
        int r = t >> 8, j = t & 255;
        red[r][j] = (double)sh[j] * (double)gwT[r * 256 + j];
    }
    __syncthreads();
    for (int s = 128; s > 0; s >>= 1) {
        if (t < 768) {
            int r = t >> 8, j = t & 255;
            if (j < s) red[r][j] += red[r][j + s];
        }
        __syncthreads();
    }
    if (t < 3) {
        double s = red[t][0];
        float pf = (float)(s + (double)b_param[t * 262 + 261]);
        pf = fminf(fmaxf(pf, -20.f), 20.f);
        double gamma = log1p(exp((double)pf)) + 1.0;
        double q = pow(0.015625 + 1e-16, gamma);
        double wv = q / (64.0 * q + 1e-8);
        srv[t] = wv * 64.0 * 1e-6;
    }
    __syncthreads();
    // ntmout dot: thread (q, m), quarter-dots of 64 terms, 4-acc fp32
    {
        int q = t >> 8, m = t & 255;
        const float* wp = w_out + (size_t)(q * 64) * 256 + m;
        float a4[4] = {0.f, 0.f, 0.f, 0.f};
        for (int d0 = 0; d0 < 64; d0 += 4) {
            float hv4[4], wv4[4];
#pragma unroll
            for (int k = 0; k < 4; ++k) hv4[k] = sh[q * 64 + d0 + k];
#pragma unroll
            for (int k = 0; k < 4; ++k) wv4[k] = wp[(size_t)(d0 + k) * 256];
#pragma unroll
            for (int k = 0; k < 4; ++k) a4[k] = fmaf(hv4[k], wv4[k], a4[k]);
        }
        dP[q][m] = (a4[0] + a4[1]) + (a4[2] + a4[3]);
    }
    __syncthreads();
    if (t < 256) {
        int m = t;
        float dotf = (dP[0][m] + dP[1][m]) + (dP[2][m] + dP[3][m]);
        double acc = (double)dotf + (double)b_out[m];
#pragma unroll
        for (int r = 0; r < 3; ++r) {
            double rsum = 0;
#pragma unroll
            for (int c = 0; c < 8; ++c) rsum += rsP[((r * 8 + c) << 8) + m];
            acc += srv[r] * rsum;
        }
        acc = fmin(fmax(acc, -20.0), 20.0);
        sNtm[m] = (float)acc;
    }
    __syncthreads();
    // conv2: 1->64 3x3 SAME + relu -> A3 NHWC bf16
    for (int p = t; p < 16384; p += 1024) {
        int co = p & 63, x4 = (p >> 6) & 15, y4 = p >> 10;
        float a = b2[co];
#pragma unroll
        for (int ky = 0; ky < 3; ++ky) {
            int gy = y4 + ky - 1;
            if ((unsigned)gy >= 16u) continue;
#pragma unroll
            for (int kx = 0; kx < 3; ++kx) {
                int gx = x4 + kx - 1;
                if ((unsigned)gx >= 16u) continue;
                a = fmaf(w2[co * 9 + ky * 3 + kx], sNtm[gy * 16 + gx], a);
            }
        }
        size_t adst = ((size_t)(b * 18 + y4 + 1) * 18 + x4 + 1) * 64 + co;
        ohi[adst] = bf16of(fmaxf(a, 0.f));
    }
}

extern "C" void kernel_launch(void* const* d_in, const int* in_sizes, int n_in,
                              void* d_out, int out_size, void* d_ws, size_t ws_size,
                              hipStream_t stream)
{
    const float* inputs   = (const float*)d_in[0];
    const float* w_conv0  = (const float*)d_in[1];
    const float* b_conv0  = (const float*)d_in[2];
    const float* w_conv1  = (const float*)d_in[3];
    const float* b_conv1  = (const float*)d_in[4];
    const float* w_enc    = (const float*)d_in[5];
    const float* b_enc    = (const float*)d_in[6];
    const float* w_conv2  = (const float*)d_in[7];
    const float* b_conv2  = (const float*)d_in[8];
    const float* w_conv3  = (const float*)d_in[9];
    const float* b_conv3  = (const float*)d_in[10];
    const float* w_conv4  = (const float*)d_in[11];
    const float* b_conv4  = (const float*)d_in[12];
    const float* w_lstm_x = (const float*)d_in[13];
    // d_in[14] = w_lstm_h : dead (h0 == 0)
    const float* b_lstm   = (const float*)d_in[15];
    const float* w_param  = (const float*)d_in[16];
    const float* b_param  = (const float*)d_in[17];
    const float* w_out_   = (const float*)d_in[18];
    const float* b_out_   = (const float*)d_in[19];

    char* ws = (char*)d_ws;
    unsigned short* a1h = (unsigned short*)(ws + OFF_A1H);
    float*  pooled = (float*)(ws + OFF_PL);
    unsigned short* a3h = (unsigned short*)(ws + OFF_A3H);
    unsigned short* a4h = a1h;                         // A4 reuses A1
    unsigned short* whi1 = (unsigned short*)(ws + OFF_W1); unsigned short* wlo1 = whi1 + 36864;
    unsigned short* whi3 = (unsigned short*)(ws + OFF_W3); unsigned short* wlo3 = whi3 + 36864;
    unsigned short* whi4 = (unsigned short*)(ws + OFF_W4); unsigned short* wlo4 = whi4 + 36864;
    double* rsP = (double*)(ws + OFF_RS);
    float*  xE  = (float*)(ws + OFF_XE);
    float*  zE  = (float*)(ws + OFF_Z);
    float*  gwT = (float*)(ws + OFF_GW);

    wprep_rowsum_kernel<<<457, 256, 0, stream>>>(
        w_conv1, w_conv3, w_conv4, w_out_, w_param,
        whi1, wlo1, whi3, wlo3, whi4, wlo4, rsP, gwT);
    halo_all_kernel<<<3200, 256, 0, stream>>>(a1h, a3h);

    conv0_pool_kernel<<<16384, 256, 0, stream>>>(inputs, w_conv0, b_conv0, a1h);
    conv1_mfma_kernel<<<512, 256, 0, stream>>>(a1h, whi1, wlo1, b_conv1, pooled);

    enc_kernel<<<64, 1024, 0, stream>>>(pooled, w_enc, b_enc, xE);
    lstm_kernel<<<192, 256, 0, stream>>>(xE, w_lstm_x, zE);
    tail_kernel<<<64, 1024, 0, stream>>>(
        zE, b_lstm, gwT, b_param, w_out_, b_out_, rsP, w_conv2, b_conv2, a3h);

    conv3_mfma_kernel<<<512, 256, 0, stream>>>(a3h, whi3, wlo3, b_conv3, a4h);
    conv4_mfma_kernel<<<1024, 256, 0, stream>>>(a4h, whi4, wlo4, b_conv4, (float*)d_out);
}

// Round 20
// 160.150 us; speedup vs baseline: 1.0732x; 1.0732x over previous
//
#include <hip/hip_runtime.h>
#include <hip/hip_bf16.h>

// ============================================================================
// Round 20: revert conv4 to the r18 proven-optimal config (occ 3). R19
// falsified the NT-immunity hypothesis: occupancy 5 re-amplified writes
// (132MB, 35MB fetch, 80us) even with NT stores. Empirical law over r15-r19:
// ROWS=4/XT=1 @ 3 blocks/CU + NT stores = WRITE exactly 64MiB, 42us. This
// file is byte-identical to r18 (best measured: 160.6us, absmax 7.629e-6).
// ============================================================================

typedef __attribute__((ext_vector_type(8))) short short8;
typedef __attribute__((ext_vector_type(4))) float f32x4;

// ---- workspace layout (bytes) ----
static const size_t OFF_A1H = 0;                       // A1/A4 NHWC hi (B,34,34,64) 9.25MB
static const size_t OFF_PL  = 18939904;                // pooled (64,64,16,16) f32 4MB
static const size_t OFF_A3H = 39911424;                // conv3 input NHWC hi (B,18,18,64)
static const size_t OFF_W1  = 45219840;                // packed whi+wlo 147,456 B/layer
static const size_t OFF_W3  = 45367296;
static const size_t OFF_W4  = 45514752;
static const size_t OFF_RS  = 45662208;                // rs_part (24,256) f64 49,152B
static const size_t OFF_XE  = 45711360;                // xE (64,256) f32 64KB
static const size_t OFF_Z   = 45776896;                // zE (64,768) f32 192KB
static const size_t OFF_GW  = 45973504;                // gwT (3,256) f32 3KB -> ~46MB

__device__ inline void bf16split(float v, unsigned short& h, unsigned short& l) {
    __hip_bfloat16 hb = __float2bfloat16(v);
    float hf = __bfloat162float(hb);
    __hip_bfloat16 lb = __float2bfloat16(v - hf);
    h = __builtin_bit_cast(unsigned short, hb);
    l = __builtin_bit_cast(unsigned short, lb);
}

__device__ inline unsigned short bf16of(float v) {
    __hip_bfloat16 hb = __float2bfloat16(v);
    return __builtin_bit_cast(unsigned short, hb);
}

// ---- prep: wpack (0..431) + rowsum partials (432..455) + gammaW (456) ----
__global__ void wprep_rowsum_kernel(
    const float* __restrict__ w1, const float* __restrict__ w3,
    const float* __restrict__ w4, const float* __restrict__ w_out,
    const float* __restrict__ w_param,
    unsigned short* __restrict__ whi1, unsigned short* __restrict__ wlo1,
    unsigned short* __restrict__ whi3, unsigned short* __restrict__ wlo3,
    unsigned short* __restrict__ whi4, unsigned short* __restrict__ wlo4,
    double* __restrict__ rsP, float* __restrict__ gwT)
{
    int blk = blockIdx.x;
    if (blk == 456) {                                  // gammaW column gather
        int t = threadIdx.x;
#pragma unroll
        for (int r = 0; r < 3; ++r)
            gwT[r * 256 + t] = w_param[(size_t)t * 3108 + r * 262 + 261];
        return;
    }
    if (blk >= 432) {                                  // rowsum partials
        int idx = blk - 432;                           // 0..23
        int r = idx >> 3, c = idx & 7;
        int m = threadIdx.x;
        const float* wp = w_out + (size_t)(256 + r * 256 + c * 32) * 256 + m;
        double s[4] = {0, 0, 0, 0};
        for (int d0 = 0; d0 < 32; d0 += 4) {
#pragma unroll
            for (int k = 0; k < 4; ++k)
                s[k] += (double)wp[(size_t)(d0 + k) * 256];
        }
        rsP[(idx << 8) + m] = (s[0] + s[1]) + (s[2] + s[3]);
        return;
    }
    int layer = blk / 144;
    int r = (blk % 144) * 256 + threadIdx.x;           // < 36864
    const float* w = layer == 0 ? w1 : (layer == 1 ? w3 : w4);
    unsigned short* hi = layer == 0 ? whi1 : (layer == 1 ? whi3 : whi4);
    unsigned short* lo = layer == 0 ? wlo1 : (layer == 1 ? wlo3 : wlo4);
    int j  = r & 7;
    int ln = (r >> 3) & 63;
    int n  = (r >> 9) & 3;
    int ch = (r >> 11) & 1;
    int t  = r >> 12;
    int lc = ln & 15, kg = ln >> 4;
    int co = n * 16 + lc;
    int ci = ch * 32 + kg * 8 + j;
    unsigned short h, l;
    bf16split(w[(co * 64 + ci) * 9 + t], h, l);
    hi[r] = h; lo[r] = l;
}

// ---- zero halo rings of a1h (S=32) and a3h (S=16) ----
__device__ inline void halo_zero_one(unsigned short* hi, int S, int idx)
{
    int P = S + 2, ring = 4 * S + 4;
    int co = idx & 63;
    int cell = (idx >> 6) % ring;
    int b = (idx >> 6) / ring;
    int y, x;
    if (cell < P)            { y = 0;     x = cell; }
    else if (cell < 2 * P)   { y = P - 1; x = cell - P; }
    else { int c2 = cell - 2 * P; y = 1 + (c2 >> 1); x = (c2 & 1) ? P - 1 : 0; }
    hi[((size_t)(b * P + y) * P + x) * 64 + co] = 0;
}

__global__ void halo_all_kernel(unsigned short* __restrict__ a1h,
                                unsigned short* __restrict__ a3h)
{
    int idx = blockIdx.x * 256 + threadIdx.x;          // 819,200 total
    if (idx < 540672) halo_zero_one(a1h, 32, idx);
    else              halo_zero_one(a3h, 16, idx - 540672);
}

// ---- fused conv0 (1->64, 3x3 SAME, relu) + avgpool2 -> A1 NHWC bf16 ----
__global__ __launch_bounds__(256) void conv0_pool_kernel(
    const float* __restrict__ in, const float* __restrict__ w,
    const float* __restrict__ bias, unsigned short* __restrict__ ohi)
{
    int idx = blockIdx.x * 256 + threadIdx.x;          // 4,194,304
    int co = idx & 63, x = (idx >> 6) & 31, y = (idx >> 11) & 31, b = idx >> 16;
    float w9[9];
#pragma unroll
    for (int t = 0; t < 9; ++t) w9[t] = w[co * 9 + t];
    float bv = bias[co];
    const float* ip = in + (size_t)b * 4096;
    float p[4][4];
#pragma unroll
    for (int r = 0; r < 4; ++r) {
        int gy = 2 * y - 1 + r;
#pragma unroll
        for (int c = 0; c < 4; ++c) {
            int gx = 2 * x - 1 + c;
            float v = 0.f;
            if ((unsigned)gy < 64u && (unsigned)gx < 64u) v = ip[gy * 64 + gx];
            p[r][c] = v;
        }
    }
    float s4 = 0.f;
#pragma unroll
    for (int dy = 0; dy < 2; ++dy)
#pragma unroll
        for (int dx = 0; dx < 2; ++dx) {
            float a = bv;
#pragma unroll
            for (int ky = 0; ky < 3; ++ky)
#pragma unroll
                for (int kx = 0; kx < 3; ++kx)
                    a = fmaf(w9[ky * 3 + kx], p[dy + ky][dx + kx], a);
            s4 += fmaxf(a, 0.f);
        }
    size_t a = ((size_t)(b * 34 + y + 1) * 34 + x + 1) * 64 + co;
    ohi[a] = bf16of(s4 * 0.25f);
}

// ---- MFMA implicit-GEMM conv body: 2-pass (ah*bh + ah*bl), A hi-only ----
// XT = x-tiles per wave. OUTMODE: 0 = NCHW f32 (nontemporal, final output),
// 1 = NHWC bf16 hi, 2 = fused relu+avgpool2 (ROWS==2).
template <int UP, int H, int ROWS, int XT, int OUTMODE>
__device__ __forceinline__ void conv_mfma_body(
    const unsigned short* __restrict__ ahi,
    const unsigned short* __restrict__ whiP, const unsigned short* __restrict__ wloP,
    const float* __restrict__ bias,
    float* __restrict__ outf, unsigned short* __restrict__ ohi)
{
    constexpr int TILEH = 4 * ROWS;
    constexpr int TILEW = 16 * XT;
    constexpr int SRC   = H >> UP;
    constexpr int PITCH = SRC + 2;
    constexpr int TPR   = H / TILEW;
    constexpr int TPC   = H / TILEH;
    constexpr int AH    = (UP ? TILEH / 2 : TILEH) + 2;
    constexpr int AW    = (UP ? TILEW / 2 : TILEW) + 2;
    constexpr int NPX   = AH * AW;

    int b  = blockIdx.x / (TPC * TPR);
    int tt = blockIdx.x % (TPC * TPR);
    int y0 = (tt / TPR) * TILEH, x0 = (tt % TPR) * TILEW;
    const int tid = threadIdx.x;
    const int wv = tid >> 6, lane = tid & 63;
    const int lc = lane & 15, kg = lane >> 4;

    __shared__ unsigned short sAhi[NPX * 64];
    __shared__ unsigned short sW[2][4096];             // [buf][hi 2048 | lo 2048]

    const int r0 = ((y0 - 1) >> UP) + 1;
    const int c0 = ((x0 - 1) >> UP) + 1;

    for (int c = tid; c < NPX * 8; c += 256) {
        int pix = c >> 3, sub = c & 7;
        int py = pix / AW, px = pix - py * AW;
        size_t g = ((size_t)(b * PITCH + r0 + py) * PITCH + (c0 + px)) * 64 + sub * 8;
        int l = (pix * 64 + sub * 8) ^ ((pix & 7) << 3);
        *(short8*)&sAhi[l] = *(const short8*)&ahi[g];
    }
    for (int c = tid; c < 512; c += 256) {
        if (c < 256) *(short8*)&sW[0][c * 8] = *(const short8*)&whiP[c * 8];
        else *(short8*)&sW[0][2048 + (c - 256) * 8] = *(const short8*)&wloP[(c - 256) * 8];
    }
    __syncthreads();

    int lxv[3][XT], lyv[ROWS + 2];
#pragma unroll
    for (int kx = 0; kx < 3; ++kx)
#pragma unroll
        for (int xt = 0; xt < XT; ++xt)
            lxv[kx][xt] = (((x0 + xt * 16 + lc + kx - 1) >> UP) + 1) - c0;
#pragma unroll
    for (int r = 0; r < ROWS + 2; ++r)
        lyv[r] = (((y0 + ROWS * wv + r - 1) >> UP) + 1) - r0;

    f32x4 acc[ROWS][XT][4];
#pragma unroll
    for (int m = 0; m < ROWS; ++m)
#pragma unroll
        for (int xt = 0; xt < XT; ++xt)
#pragma unroll
            for (int n = 0; n < 4; ++n) acc[m][xt][n] = f32x4{0.f, 0.f, 0.f, 0.f};

#pragma unroll
    for (int k = 0; k < 18; ++k) {                     // k = t*2 + ch
        if (k + 1 < 18) {                              // prefetch next W slice
            int slb = (k + 1) * 2048;
            for (int c = tid; c < 512; c += 256) {
                if (c < 256) *(short8*)&sW[(k + 1) & 1][c * 8] =
                    *(const short8*)&whiP[slb + c * 8];
                else *(short8*)&sW[(k + 1) & 1][2048 + (c - 256) * 8] =
                    *(const short8*)&wloP[slb + (c - 256) * 8];
            }
        }
        const int t = k >> 1, ch = k & 1;
        const int ky = t / 3, kx = t - ky * 3;
        short8 ah[ROWS][XT];
#pragma unroll
        for (int m = 0; m < ROWS; ++m)
#pragma unroll
            for (int xt = 0; xt < XT; ++xt) {
                int p = lyv[ky + m] * AW + lxv[kx][xt];
                int i = (p * 64 + ch * 32 + kg * 8) ^ ((p & 7) << 3);
                ah[m][xt] = *(const short8*)&sAhi[i];
            }
        const unsigned short* wb = &sW[k & 1][0];
#pragma unroll
        for (int n = 0; n < 4; ++n) {
            short8 bh = *(const short8*)&wb[(n * 64 + lane) * 8];
            short8 bl = *(const short8*)&wb[2048 + (n * 64 + lane) * 8];
#pragma unroll
            for (int xt = 0; xt < XT; ++xt)
#pragma unroll
                for (int m = 0; m < ROWS; ++m) {
                    acc[m][xt][n] = __builtin_amdgcn_mfma_f32_16x16x32_bf16(ah[m][xt], bh, acc[m][xt][n], 0, 0, 0);
                    acc[m][xt][n] = __builtin_amdgcn_mfma_f32_16x16x32_bf16(ah[m][xt], bl, acc[m][xt][n], 0, 0, 0);
                }
        }
        __syncthreads();
    }

    // epilogue: D col(lane&15)=co frag idx, row(kg*4+reg)=pixel-x (verified r4)
    if (OUTMODE == 1) {
        const int opitch = H + 2;
#pragma unroll
        for (int n = 0; n < 4; ++n) {
            int co = n * 16 + lc;
            float bv = bias[co];
#pragma unroll
            for (int m = 0; m < ROWS; ++m)
#pragma unroll
                for (int xt = 0; xt < XT; ++xt) {
                    int row = y0 + ROWS * wv + m, cb = x0 + xt * 16 + kg * 4;
                    f32x4 v = acc[m][xt][n];
#pragma unroll
                    for (int j = 0; j < 4; ++j) {
                        float val = fmaxf(v[j] + bv, 0.f);
                        size_t a = ((size_t)(b * opitch + row + 1) * opitch + cb + j + 1) * 64 + co;
                        ohi[a] = bf16of(val);
                    }
                }
        }
    } else if (OUTMODE == 2) {                         // fused relu+avgpool2 (ROWS==2)
#pragma unroll
        for (int n = 0; n < 4; ++n) {
            int co = n * 16 + lc;
            float bv = bias[co];
#pragma unroll
            for (int xt = 0; xt < XT; ++xt) {
                f32x4 v0 = acc[0][xt][n], v1 = acc[1][xt][n];
                float r00 = fmaxf(v0.x + bv, 0.f), r01 = fmaxf(v0.y + bv, 0.f);
                float r02 = fmaxf(v0.z + bv, 0.f), r03 = fmaxf(v0.w + bv, 0.f);
                float r10 = fmaxf(v1.x + bv, 0.f), r11 = fmaxf(v1.y + bv, 0.f);
                float r12 = fmaxf(v1.z + bv, 0.f), r13 = fmaxf(v1.w + bv, 0.f);
                float p0 = ((r00 + r01) + (r10 + r11)) * 0.25f;
                float p1 = ((r02 + r03) + (r12 + r13)) * 0.25f;
                int py = (y0 >> 1) + wv;
                int px = ((x0 + xt * 16) >> 1) + kg * 2;
                float* op = outf + ((size_t)(b * 64 + co) * 16 + py) * 16 + px;
                op[0] = p0; op[1] = p1;
            }
        }
    } else {                                           // final output: stream past L2
#pragma unroll
        for (int n = 0; n < 4; ++n) {
            int co = n * 16 + lc;
            float bv = bias[co];
#pragma unroll
            for (int m = 0; m < ROWS; ++m)
#pragma unroll
                for (int xt = 0; xt < XT; ++xt) {
                    int row = y0 + ROWS * wv + m, cb = x0 + xt * 16 + kg * 4;
                    f32x4 v = acc[m][xt][n], res;
                    res.x = fmaxf(v.x + bv, 0.f);
                    res.y = fmaxf(v.y + bv, 0.f);
                    res.z = fmaxf(v.z + bv, 0.f);
                    res.w = fmaxf(v.w + bv, 0.f);
                    __builtin_nontemporal_store(res,
                        (f32x4*)&outf[((size_t)(b * 64 + co) * H + row) * H + cb]);
                }
        }
    }
}

__global__ __launch_bounds__(256, 4) void conv1_mfma_kernel(
    const unsigned short* __restrict__ ahi,
    const unsigned short* __restrict__ whiP, const unsigned short* __restrict__ wloP,
    const float* __restrict__ bias, float* __restrict__ pooled)
{ conv_mfma_body<0, 32, 2, 1, 2>(ahi, whiP, wloP, bias, pooled, nullptr); }

__global__ __launch_bounds__(256, 6) void conv3_mfma_kernel(
    const unsigned short* __restrict__ ahi,
    const unsigned short* __restrict__ whiP, const unsigned short* __restrict__ wloP,
    const float* __restrict__ bias, unsigned short* __restrict__ ohi)
{ conv_mfma_body<1, 32, 2, 1, 1>(ahi, whiP, wloP, bias, nullptr, ohi); }

// conv4: r18 proven-optimal (16x16 tile, ROWS=4, occ 3, NT stores)
__global__ __launch_bounds__(256, 3) void conv4_mfma_kernel(
    const unsigned short* __restrict__ ahi,
    const unsigned short* __restrict__ whiP, const unsigned short* __restrict__ wloP,
    const float* __restrict__ bias, float* __restrict__ outf)
{ conv_mfma_body<1, 64, 4, 1, 0>(ahi, whiP, wloP, bias, outf, nullptr); }

// ---- enc: pooled (b,64,16,16) -> xE (64,256) ----
__global__ __launch_bounds__(1024) void enc_kernel(
    const float* __restrict__ pooled, const float* __restrict__ w_enc,
    const float* __restrict__ b_enc, float* __restrict__ xE)
{
    int b = blockIdx.x, t = threadIdx.x;
    __shared__ float sE[16384];
    __shared__ float eP[4][256];
    {
        const f32x4* src = (const f32x4*)(pooled + (size_t)b * 16384);
        f32x4* dst = (f32x4*)sE;
#pragma unroll
        for (int p = t; p < 4096; p += 1024) dst[p] = src[p];
    }
    __syncthreads();
    {
        int g = t >> 8, j = t & 255;
        int y = j >> 4, x = j & 15;
        float a0 = 0.f, a1 = 0.f;
        for (int cc = 0; cc < 16; ++cc) {
            int ci = g * 16 + cc;
#pragma unroll
            for (int ky = 0; ky < 3; ++ky) {
                int gy = y + ky - 1;
                if ((unsigned)gy >= 16u) continue;
#pragma unroll
                for (int kx = 0; kx < 3; ++kx) {
                    int gx = x + kx - 1;
                    if ((unsigned)gx >= 16u) continue;
                    float pr = w_enc[ci * 9 + ky * 3 + kx] * sE[ci * 256 + gy * 16 + gx];
                    if (cc & 1) a1 += pr; else a0 += pr;
                }
            }
        }
        eP[g][j] = a0 + a1;
    }
    __syncthreads();
    if (t < 256) {
        float v = ((eP[0][t] + eP[1][t]) + (eP[2][t] + eP[3][t])) + b_enc[0];
        xE[b * 256 + t] = fmaxf(v, 0.f);
    }
}

// ---- lstm z-GEMM: 192 blocks = (gate g, image b); thread = column j ----
__global__ __launch_bounds__(256) void lstm_kernel(
    const float* __restrict__ xE, const float* __restrict__ wx,
    float* __restrict__ zE)
{
    int blk = blockIdx.x;
    int g = blk >> 6, b = blk & 63;
    int goff = (g == 0) ? 0 : (g == 1 ? 512 : 768);
    int j = threadIdx.x;
    __shared__ float sx[256];
    sx[j] = xE[b * 256 + j];
    __syncthreads();
    const float* wp = wx + goff + j;
    float acc[8];
#pragma unroll
    for (int k = 0; k < 8; ++k) acc[k] = 0.f;
    for (int d0 = 0; d0 < 256; d0 += 8) {
        float xv[8], wv[8];
#pragma unroll
        for (int k = 0; k < 8; ++k) xv[k] = sx[d0 + k];
#pragma unroll
        for (int k = 0; k < 8; ++k) wv[k] = wp[(size_t)(d0 + k) * 1024];
#pragma unroll
        for (int k = 0; k < 8; ++k) acc[k] = fmaf(xv[k], wv[k], acc[k]);
    }
    zE[b * 768 + g * 256 + j] = ((acc[0] + acc[1]) + (acc[2] + acc[3]))
                              + ((acc[4] + acc[5]) + (acc[6] + acc[7]));
}

// ---- tail: gates + gamma + ntmout + conv2 -> A3 NHWC bf16 (block = image) ----
__global__ __launch_bounds__(1024) void tail_kernel(
    const float* __restrict__ zE, const float* __restrict__ bl,
    const float* __restrict__ gwT, const float* __restrict__ b_param,
    const float* __restrict__ w_out, const float* __restrict__ b_out,
    const double* __restrict__ rsP, const float* __restrict__ w2,
    const float* __restrict__ b2, unsigned short* __restrict__ ohi)
{
    int b = blockIdx.x, t = threadIdx.x;
    __shared__ float  sh[256];
    __shared__ double red[3][256];
    __shared__ double srv[3];
    __shared__ float  dP[4][256];
    __shared__ float  sNtm[256];

    if (t < 256) {                                     // gates (fp64 math)
        int j = t;
        float zif = (float)((double)zE[b * 768 + j]       + (double)bl[j]);
        float zgf = (float)((double)zE[b * 768 + 256 + j] + (double)bl[512 + j]);
        float zof = (float)((double)zE[b * 768 + 512 + j] + (double)bl[768 + j]);
        double c = (1.0 / (1.0 + exp(-(double)zif))) * tanh((double)zgf);
        float cf = (float)c;
        double hh = (1.0 / (1.0 + exp(-(double)zof))) * tanh((double)cf);
        sh[j] = (float)hh;
    }
    __syncthreads();
    // gamma: products (contiguous gwT) then LDS tree reduce
    if (t < 768) {
        int r = t >> 8, j = t & 255;
        red[r][j] = (double)sh[j] * (double)gwT[r * 256 + j];
    }
    __syncthreads();
    for (int s = 128; s > 0; s >>= 1) {
        if (t < 768) {
            int r = t >> 8, j = t & 255;
            if (j < s) red[r][j] += red[r][j + s];
        }
        __syncthreads();
    }
    if (t < 3) {
        double s = red[t][0];
        float pf = (float)(s + (double)b_param[t * 262 + 261]);
        pf = fminf(fmaxf(pf, -20.f), 20.f);
        double gamma = log1p(exp((double)pf)) + 1.0;
        double q = pow(0.015625 + 1e-16, gamma);
        double wv = q / (64.0 * q + 1e-8);
        srv[t] = wv * 64.0 * 1e-6;
    }
    __syncthreads();
    // ntmout dot: thread (q, m), quarter-dots of 64 terms, 4-acc fp32
    {
        int q = t >> 8, m = t & 255;
        const float* wp = w_out + (size_t)(q * 64) * 256 + m;
        float a4[4] = {0.f, 0.f, 0.f, 0.f};
        for (int d0 = 0; d0 < 64; d0 += 4) {
            float hv4[4], wv4[4];
#pragma unroll
            for (int k = 0; k < 4; ++k) hv4[k] = sh[q * 64 + d0 + k];
#pragma unroll
            for (int k = 0; k < 4; ++k) wv4[k] = wp[(size_t)(d0 + k) * 256];
#pragma unroll
            for (int k = 0; k < 4; ++k) a4[k] = fmaf(hv4[k], wv4[k], a4[k]);
        }
        dP[q][m] = (a4[0] + a4[1]) + (a4[2] + a4[3]);
    }
    __syncthreads();
    if (t < 256) {
        int m = t;
        float dotf = (dP[0][m] + dP[1][m]) + (dP[2][m] + dP[3][m]);
        double acc = (double)dotf + (double)b_out[m];
#pragma unroll
        for (int r = 0; r < 3; ++r) {
            double rsum = 0;
#pragma unroll
            for (int c = 0; c < 8; ++c) rsum += rsP[((r * 8 + c) << 8) + m];
            acc += srv[r] * rsum;
        }
        acc = fmin(fmax(acc, -20.0), 20.0);
        sNtm[m] = (float)acc;
    }
    __syncthreads();
    // conv2: 1->64 3x3 SAME + relu -> A3 NHWC bf16
    for (int p = t; p < 16384; p += 1024) {
        int co = p & 63, x4 = (p >> 6) & 15, y4 = p >> 10;
        float a = b2[co];
#pragma unroll
        for (int ky = 0; ky < 3; ++ky) {
            int gy = y4 + ky - 1;
            if ((unsigned)gy >= 16u) continue;
#pragma unroll
            for (int kx = 0; kx < 3; ++kx) {
                int gx = x4 + kx - 1;
                if ((unsigned)gx >= 16u) continue;
                a = fmaf(w2[co * 9 + ky * 3 + kx], sNtm[gy * 16 + gx], a);
            }
        }
        size_t adst = ((size_t)(b * 18 + y4 + 1) * 18 + x4 + 1) * 64 + co;
        ohi[adst] = bf16of(fmaxf(a, 0.f));
    }
}

extern "C" void kernel_launch(void* const* d_in, const int* in_sizes, int n_in,
                              void* d_out, int out_size, void* d_ws, size_t ws_size,
                              hipStream_t stream)
{
    const float* inputs   = (const float*)d_in[0];
    const float* w_conv0  = (const float*)d_in[1];
    const float* b_conv0  = (const float*)d_in[2];
    const float* w_conv1  = (const float*)d_in[3];
    const float* b_conv1  = (const float*)d_in[4];
    const float* w_enc    = (const float*)d_in[5];
    const float* b_enc    = (const float*)d_in[6];
    const float* w_conv2  = (const float*)d_in[7];
    const float* b_conv2  = (const float*)d_in[8];
    const float* w_conv3  = (const float*)d_in[9];
    const float* b_conv3  = (const float*)d_in[10];
    const float* w_conv4  = (const float*)d_in[11];
    const float* b_conv4  = (const float*)d_in[12];
    const float* w_lstm_x = (const float*)d_in[13];
    // d_in[14] = w_lstm_h : dead (h0 == 0)
    const float* b_lstm   = (const float*)d_in[15];
    const float* w_param  = (const float*)d_in[16];
    const float* b_param  = (const float*)d_in[17];
    const float* w_out_   = (const float*)d_in[18];
    const float* b_out_   = (const float*)d_in[19];

    char* ws = (char*)d_ws;
    unsigned short* a1h = (unsigned short*)(ws + OFF_A1H);
    float*  pooled = (float*)(ws + OFF_PL);
    unsigned short* a3h = (unsigned short*)(ws + OFF_A3H);
    unsigned short* a4h = a1h;                         // A4 reuses A1
    unsigned short* whi1 = (unsigned short*)(ws + OFF_W1); unsigned short* wlo1 = whi1 + 36864;
    unsigned short* whi3 = (unsigned short*)(ws + OFF_W3); unsigned short* wlo3 = whi3 + 36864;
    unsigned short* whi4 = (unsigned short*)(ws + OFF_W4); unsigned short* wlo4 = whi4 + 36864;
    double* rsP = (double*)(ws + OFF_RS);
    float*  xE  = (float*)(ws + OFF_XE);
    float*  zE  = (float*)(ws + OFF_Z);
    float*  gwT = (float*)(ws + OFF_GW);

    wprep_rowsum_kernel<<<457, 256, 0, stream>>>(
        w_conv1, w_conv3, w_conv4, w_out_, w_param,
        whi1, wlo1, whi3, wlo3, whi4, wlo4, rsP, gwT);
    halo_all_kernel<<<3200, 256, 0, stream>>>(a1h, a3h);

    conv0_pool_kernel<<<16384, 256, 0, stream>>>(inputs, w_conv0, b_conv0, a1h);
    conv1_mfma_kernel<<<512, 256, 0, stream>>>(a1h, whi1, wlo1, b_conv1, pooled);

    enc_kernel<<<64, 1024, 0, stream>>>(pooled, w_enc, b_enc, xE);
    lstm_kernel<<<192, 256, 0, stream>>>(xE, w_lstm_x, zE);
    tail_kernel<<<64, 1024, 0, stream>>>(
        zE, b_lstm, gwT, b_param, w_out_, b_out_, rsP, w_conv2, b_conv2, a3h);

    conv3_mfma_kernel<<<512, 256, 0, stream>>>(a3h, whi3, wlo3, b_conv3, a4h);
    conv4_mfma_kernel<<<1024, 256, 0, stream>>>(a4h, whi4, wlo4, b_conv4, (float*)d_out);
}

// Round 21
// 159.321 us; speedup vs baseline: 1.0788x; 1.0052x over previous
//
#include <hip/hip_runtime.h>
#include <hip/hip_bf16.h>

// ============================================================================
// Round 21: final one-variable test — conv4 occupancy 3 -> 4 (untested middle
// of the measured bracket: occ3=clean 42us / occ5=amplified 80us, both with
// NT stores). Wave stores cover complete 256B rows, so amplification scales
// with the concurrent tile window, not partial lines; occ4 may have headroom.
// Pre-committed: WRITE stays 64MiB -> keep (~36us); WRITE balloons -> revert
// to r20 and declare converged. Everything else byte-identical to r20.
// ============================================================================

typedef __attribute__((ext_vector_type(8))) short short8;
typedef __attribute__((ext_vector_type(4))) float f32x4;

// ---- workspace layout (bytes) ----
static const size_t OFF_A1H = 0;                       // A1/A4 NHWC hi (B,34,34,64) 9.25MB
static const size_t OFF_PL  = 18939904;                // pooled (64,64,16,16) f32 4MB
static const size_t OFF_A3H = 39911424;                // conv3 input NHWC hi (B,18,18,64)
static const size_t OFF_W1  = 45219840;                // packed whi+wlo 147,456 B/layer
static const size_t OFF_W3  = 45367296;
static const size_t OFF_W4  = 45514752;
static const size_t OFF_RS  = 45662208;                // rs_part (24,256) f64 49,152B
static const size_t OFF_XE  = 45711360;                // xE (64,256) f32 64KB
static const size_t OFF_Z   = 45776896;                // zE (64,768) f32 192KB
static const size_t OFF_GW  = 45973504;                // gwT (3,256) f32 3KB -> ~46MB

__device__ inline void bf16split(float v, unsigned short& h, unsigned short& l) {
    __hip_bfloat16 hb = __float2bfloat16(v);
    float hf = __bfloat162float(hb);
    __hip_bfloat16 lb = __float2bfloat16(v - hf);
    h = __builtin_bit_cast(unsigned short, hb);
    l = __builtin_bit_cast(unsigned short, lb);
}

__device__ inline unsigned short bf16of(float v) {
    __hip_bfloat16 hb = __float2bfloat16(v);
    return __builtin_bit_cast(unsigned short, hb);
}

// ---- prep: wpack (0..431) + rowsum partials (432..455) + gammaW (456) ----
__global__ void wprep_rowsum_kernel(
    const float* __restrict__ w1, const float* __restrict__ w3,
    const float* __restrict__ w4, const float* __restrict__ w_out,
    const float* __restrict__ w_param,
    unsigned short* __restrict__ whi1, unsigned short* __restrict__ wlo1,
    unsigned short* __restrict__ whi3, unsigned short* __restrict__ wlo3,
    unsigned short* __restrict__ whi4, unsigned short* __restrict__ wlo4,
    double* __restrict__ rsP, float* __restrict__ gwT)
{
    int blk = blockIdx.x;
    if (blk == 456) {                                  // gammaW column gather
        int t = threadIdx.x;
#pragma unroll
        for (int r = 0; r < 3; ++r)
            gwT[r * 256 + t] = w_param[(size_t)t * 3108 + r * 262 + 261];
        return;
    }
    if (blk >= 432) {                                  // rowsum partials
        int idx = blk - 432;                           // 0..23
        int r = idx >> 3, c = idx & 7;
        int m = threadIdx.x;
        const float* wp = w_out + (size_t)(256 + r * 256 + c * 32) * 256 + m;
        double s[4] = {0, 0, 0, 0};
        for (int d0 = 0; d0 < 32; d0 += 4) {
#pragma unroll
            for (int k = 0; k < 4; ++k)
                s[k] += (double)wp[(size_t)(d0 + k) * 256];
        }
        rsP[(idx << 8) + m] = (s[0] + s[1]) + (s[2] + s[3]);
        return;
    }
    int layer = blk / 144;
    int r = (blk % 144) * 256 + threadIdx.x;           // < 36864
    const float* w = layer == 0 ? w1 : (layer == 1 ? w3 : w4);
    unsigned short* hi = layer == 0 ? whi1 : (layer == 1 ? whi3 : whi4);
    unsigned short* lo = layer == 0 ? wlo1 : (layer == 1 ? wlo3 : wlo4);
    int j  = r & 7;
    int ln = (r >> 3) & 63;
    int n  = (r >> 9) & 3;
    int ch = (r >> 11) & 1;
    int t  = r >> 12;
    int lc = ln & 15, kg = ln >> 4;
    int co = n * 16 + lc;
    int ci = ch * 32 + kg * 8 + j;
    unsigned short h, l;
    bf16split(w[(co * 64 + ci) * 9 + t], h, l);
    hi[r] = h; lo[r] = l;
}

// ---- zero halo rings of a1h (S=32) and a3h (S=16) ----
__device__ inline void halo_zero_one(unsigned short* hi, int S, int idx)
{
    int P = S + 2, ring = 4 * S + 4;
    int co = idx & 63;
    int cell = (idx >> 6) % ring;
    int b = (idx >> 6) / ring;
    int y, x;
    if (cell < P)            { y = 0;     x = cell; }
    else if (cell < 2 * P)   { y = P - 1; x = cell - P; }
    else { int c2 = cell - 2 * P; y = 1 + (c2 >> 1); x = (c2 & 1) ? P - 1 : 0; }
    hi[((size_t)(b * P + y) * P + x) * 64 + co] = 0;
}

__global__ void halo_all_kernel(unsigned short* __restrict__ a1h,
                                unsigned short* __restrict__ a3h)
{
    int idx = blockIdx.x * 256 + threadIdx.x;          // 819,200 total
    if (idx < 540672) halo_zero_one(a1h, 32, idx);
    else              halo_zero_one(a3h, 16, idx - 540672);
}

// ---- fused conv0 (1->64, 3x3 SAME, relu) + avgpool2 -> A1 NHWC bf16 ----
__global__ __launch_bounds__(256) void conv0_pool_kernel(
    const float* __restrict__ in, const float* __restrict__ w,
    const float* __restrict__ bias, unsigned short* __restrict__ ohi)
{
    int idx = blockIdx.x * 256 + threadIdx.x;          // 4,194,304
    int co = idx & 63, x = (idx >> 6) & 31, y = (idx >> 11) & 31, b = idx >> 16;
    float w9[9];
#pragma unroll
    for (int t = 0; t < 9; ++t) w9[t] = w[co * 9 + t];
    float bv = bias[co];
    const float* ip = in + (size_t)b * 4096;
    float p[4][4];
#pragma unroll
    for (int r = 0; r < 4; ++r) {
        int gy = 2 * y - 1 + r;
#pragma unroll
        for (int c = 0; c < 4; ++c) {
            int gx = 2 * x - 1 + c;
            float v = 0.f;
            if ((unsigned)gy < 64u && (unsigned)gx < 64u) v = ip[gy * 64 + gx];
            p[r][c] = v;
        }
    }
    float s4 = 0.f;
#pragma unroll
    for (int dy = 0; dy < 2; ++dy)
#pragma unroll
        for (int dx = 0; dx < 2; ++dx) {
            float a = bv;
#pragma unroll
            for (int ky = 0; ky < 3; ++ky)
#pragma unroll
                for (int kx = 0; kx < 3; ++kx)
                    a = fmaf(w9[ky * 3 + kx], p[dy + ky][dx + kx], a);
            s4 += fmaxf(a, 0.f);
        }
    size_t a = ((size_t)(b * 34 + y + 1) * 34 + x + 1) * 64 + co;
    ohi[a] = bf16of(s4 * 0.25f);
}

// ---- MFMA implicit-GEMM conv body: 2-pass (ah*bh + ah*bl), A hi-only ----
// XT = x-tiles per wave. OUTMODE: 0 = NCHW f32 (nontemporal, final output),
// 1 = NHWC bf16 hi, 2 = fused relu+avgpool2 (ROWS==2).
template <int UP, int H, int ROWS, int XT, int OUTMODE>
__device__ __forceinline__ void conv_mfma_body(
    const unsigned short* __restrict__ ahi,
    const unsigned short* __restrict__ whiP, const unsigned short* __restrict__ wloP,
    const float* __restrict__ bias,
    float* __restrict__ outf, unsigned short* __restrict__ ohi)
{
    constexpr int TILEH = 4 * ROWS;
    constexpr int TILEW = 16 * XT;
    constexpr int SRC   = H >> UP;
    constexpr int PITCH = SRC + 2;
    constexpr int TPR   = H / TILEW;
    constexpr int TPC   = H / TILEH;
    constexpr int AH    = (UP ? TILEH / 2 : TILEH) + 2;
    constexpr int AW    = (UP ? TILEW / 2 : TILEW) + 2;
    constexpr int NPX   = AH * AW;

    int b  = blockIdx.x / (TPC * TPR);
    int tt = blockIdx.x % (TPC * TPR);
    int y0 = (tt / TPR) * TILEH, x0 = (tt % TPR) * TILEW;
    const int tid = threadIdx.x;
    const int wv = tid >> 6, lane = tid & 63;
    const int lc = lane & 15, kg = lane >> 4;

    __shared__ unsigned short sAhi[NPX * 64];
    __shared__ unsigned short sW[2][4096];             // [buf][hi 2048 | lo 2048]

    const int r0 = ((y0 - 1) >> UP) + 1;
    const int c0 = ((x0 - 1) >> UP) + 1;

    for (int c = tid; c < NPX * 8; c += 256) {
        int pix = c >> 3, sub = c & 7;
        int py = pix / AW, px = pix - py * AW;
        size_t g = ((size_t)(b * PITCH + r0 + py) * PITCH + (c0 + px)) * 64 + sub * 8;
        int l = (pix * 64 + sub * 8) ^ ((pix & 7) << 3);
        *(short8*)&sAhi[l] = *(const short8*)&ahi[g];
    }
    for (int c = tid; c < 512; c += 256) {
        if (c < 256) *(short8*)&sW[0][c * 8] = *(const short8*)&whiP[c * 8];
        else *(short8*)&sW[0][2048 + (c - 256) * 8] = *(const short8*)&wloP[(c - 256) * 8];
    }
    __syncthreads();

    int lxv[3][XT], lyv[ROWS + 2];
#pragma unroll
    for (int kx = 0; kx < 3; ++kx)
#pragma unroll
        for (int xt = 0; xt < XT; ++xt)
            lxv[kx][xt] = (((x0 + xt * 16 + lc + kx - 1) >> UP) + 1) - c0;
#pragma unroll
    for (int r = 0; r < ROWS + 2; ++r)
        lyv[r] = (((y0 + ROWS * wv + r - 1) >> UP) + 1) - r0;

    f32x4 acc[ROWS][XT][4];
#pragma unroll
    for (int m = 0; m < ROWS; ++m)
#pragma unroll
        for (int xt = 0; xt < XT; ++xt)
#pragma unroll
            for (int n = 0; n < 4; ++n) acc[m][xt][n] = f32x4{0.f, 0.f, 0.f, 0.f};

#pragma unroll
    for (int k = 0; k < 18; ++k) {                     // k = t*2 + ch
        if (k + 1 < 18) {                              // prefetch next W slice
            int slb = (k + 1) * 2048;
            for (int c = tid; c < 512; c += 256) {
                if (c < 256) *(short8*)&sW[(k + 1) & 1][c * 8] =
                    *(const short8*)&whiP[slb + c * 8];
                else *(short8*)&sW[(k + 1) & 1][2048 + (c - 256) * 8] =
                    *(const short8*)&wloP[slb + (c - 256) * 8];
            }
        }
        const int t = k >> 1, ch = k & 1;
        const int ky = t / 3, kx = t - ky * 3;
        short8 ah[ROWS][XT];
#pragma unroll
        for (int m = 0; m < ROWS; ++m)
#pragma unroll
            for (int xt = 0; xt < XT; ++xt) {
                int p = lyv[ky + m] * AW + lxv[kx][xt];
                int i = (p * 64 + ch * 32 + kg * 8) ^ ((p & 7) << 3);
                ah[m][xt] = *(const short8*)&sAhi[i];
            }
        const unsigned short* wb = &sW[k & 1][0];
#pragma unroll
        for (int n = 0; n < 4; ++n) {
            short8 bh = *(const short8*)&wb[(n * 64 + lane) * 8];
            short8 bl = *(const short8*)&wb[2048 + (n * 64 + lane) * 8];
#pragma unroll
            for (int xt = 0; xt < XT; ++xt)
#pragma unroll
                for (int m = 0; m < ROWS; ++m) {
                    acc[m][xt][n] = __builtin_amdgcn_mfma_f32_16x16x32_bf16(ah[m][xt], bh, acc[m][xt][n], 0, 0, 0);
                    acc[m][xt][n] = __builtin_amdgcn_mfma_f32_16x16x32_bf16(ah[m][xt], bl, acc[m][xt][n], 0, 0, 0);
                }
        }
        __syncthreads();
    }

    // epilogue: D col(lane&15)=co frag idx, row(kg*4+reg)=pixel-x (verified r4)
    if (OUTMODE == 1) {
        const int opitch = H + 2;
#pragma unroll
        for (int n = 0; n < 4; ++n) {
            int co = n * 16 + lc;
            float bv = bias[co];
#pragma unroll
            for (int m = 0; m < ROWS; ++m)
#pragma unroll
                for (int xt = 0; xt < XT; ++xt) {
                    int row = y0 + ROWS * wv + m, cb = x0 + xt * 16 + kg * 4;
                    f32x4 v = acc[m][xt][n];
#pragma unroll
                    for (int j = 0; j < 4; ++j) {
                        float val = fmaxf(v[j] + bv, 0.f);
                        size_t a = ((size_t)(b * opitch + row + 1) * opitch + cb + j + 1) * 64 + co;
                        ohi[a] = bf16of(val);
                    }
                }
        }
    } else if (OUTMODE == 2) {                         // fused relu+avgpool2 (ROWS==2)
#pragma unroll
        for (int n = 0; n < 4; ++n) {
            int co = n * 16 + lc;
            float bv = bias[co];
#pragma unroll
            for (int xt = 0; xt < XT; ++xt) {
                f32x4 v0 = acc[0][xt][n], v1 = acc[1][xt][n];
                float r00 = fmaxf(v0.x + bv, 0.f), r01 = fmaxf(v0.y + bv, 0.f);
                float r02 = fmaxf(v0.z + bv, 0.f), r03 = fmaxf(v0.w + bv, 0.f);
                float r10 = fmaxf(v1.x + bv, 0.f), r11 = fmaxf(v1.y + bv, 0.f);
                float r12 = fmaxf(v1.z + bv, 0.f), r13 = fmaxf(v1.w + bv, 0.f);
                float p0 = ((r00 + r01) + (r10 + r11)) * 0.25f;
                float p1 = ((r02 + r03) + (r12 + r13)) * 0.25f;
                int py = (y0 >> 1) + wv;
                int px = ((x0 + xt * 16) >> 1) + kg * 2;
                float* op = outf + ((size_t)(b * 64 + co) * 16 + py) * 16 + px;
                op[0] = p0; op[1] = p1;
            }
        }
    } else {                                           // final output: stream past L2
#pragma unroll
        for (int n = 0; n < 4; ++n) {
            int co = n * 16 + lc;
            float bv = bias[co];
#pragma unroll
            for (int m = 0; m < ROWS; ++m)
#pragma unroll
                for (int xt = 0; xt < XT; ++xt) {
                    int row = y0 + ROWS * wv + m, cb = x0 + xt * 16 + kg * 4;
                    f32x4 v = acc[m][xt][n], res;
                    res.x = fmaxf(v.x + bv, 0.f);
                    res.y = fmaxf(v.y + bv, 0.f);
                    res.z = fmaxf(v.z + bv, 0.f);
                    res.w = fmaxf(v.w + bv, 0.f);
                    __builtin_nontemporal_store(res,
                        (f32x4*)&outf[((size_t)(b * 64 + co) * H + row) * H + cb]);
                }
        }
    }
}

__global__ __launch_bounds__(256, 4) void conv1_mfma_kernel(
    const unsigned short* __restrict__ ahi,
    const unsigned short* __restrict__ whiP, const unsigned short* __restrict__ wloP,
    const float* __restrict__ bias, float* __restrict__ pooled)
{ conv_mfma_body<0, 32, 2, 1, 2>(ahi, whiP, wloP, bias, pooled, nullptr); }

__global__ __launch_bounds__(256, 6) void conv3_mfma_kernel(
    const unsigned short* __restrict__ ahi,
    const unsigned short* __restrict__ whiP, const unsigned short* __restrict__ wloP,
    const float* __restrict__ bias, unsigned short* __restrict__ ohi)
{ conv_mfma_body<1, 32, 2, 1, 1>(ahi, whiP, wloP, bias, nullptr, ohi); }

// conv4: ROWS=4/XT=1 + NT stores, occupancy 4 (one-variable test)
__global__ __launch_bounds__(256, 4) void conv4_mfma_kernel(
    const unsigned short* __restrict__ ahi,
    const unsigned short* __restrict__ whiP, const unsigned short* __restrict__ wloP,
    const float* __restrict__ bias, float* __restrict__ outf)
{ conv_mfma_body<1, 64, 4, 1, 0>(ahi, whiP, wloP, bias, outf, nullptr); }

// ---- enc: pooled (b,64,16,16) -> xE (64,256) ----
__global__ __launch_bounds__(1024) void enc_kernel(
    const float* __restrict__ pooled, const float* __restrict__ w_enc,
    const float* __restrict__ b_enc, float* __restrict__ xE)
{
    int b = blockIdx.x, t = threadIdx.x;
    __shared__ float sE[16384];
    __shared__ float eP[4][256];
    {
        const f32x4* src = (const f32x4*)(pooled + (size_t)b * 16384);
        f32x4* dst = (f32x4*)sE;
#pragma unroll
        for (int p = t; p < 4096; p += 1024) dst[p] = src[p];
    }
    __syncthreads();
    {
        int g = t >> 8, j = t & 255;
        int y = j >> 4, x = j & 15;
        float a0 = 0.f, a1 = 0.f;
        for (int cc = 0; cc < 16; ++cc) {
            int ci = g * 16 + cc;
#pragma unroll
            for (int ky = 0; ky < 3; ++ky) {
                int gy = y + ky - 1;
                if ((unsigned)gy >= 16u) continue;
#pragma unroll
                for (int kx = 0; kx < 3; ++kx) {
                    int gx = x + kx - 1;
                    if ((unsigned)gx >= 16u) continue;
                    float pr = w_enc[ci * 9 + ky * 3 + kx] * sE[ci * 256 + gy * 16 + gx];
                    if (cc & 1) a1 += pr; else a0 += pr;
                }
            }
        }
        eP[g][j] = a0 + a1;
    }
    __syncthreads();
    if (t < 256) {
        float v = ((eP[0][t] + eP[1][t]) + (eP[2][t] + eP[3][t])) + b_enc[0];
        xE[b * 256 + t] = fmaxf(v, 0.f);
    }
}

// ---- lstm z-GEMM: 192 blocks = (gate g, image b); thread = column j ----
__global__ __launch_bounds__(256) void lstm_kernel(
    const float* __restrict__ xE, const float* __restrict__ wx,
    float* __restrict__ zE)
{
    int blk = blockIdx.x;
    int g = blk >> 6, b = blk & 63;
    int goff = (g == 0) ? 0 : (g == 1 ? 512 : 768);
    int j = threadIdx.x;
    __shared__ float sx[256];
    sx[j] = xE[b * 256 + j];
    __syncthreads();
    const float* wp = wx + goff + j;
    float acc[8];
#pragma unroll
    for (int k = 0; k < 8; ++k) acc[k] = 0.f;
    for (int d0 = 0; d0 < 256; d0 += 8) {
        float xv[8], wv[8];
#pragma unroll
        for (int k = 0; k < 8; ++k) xv[k] = sx[d0 + k];
#pragma unroll
        for (int k = 0; k < 8; ++k) wv[k] = wp[(size_t)(d0 + k) * 1024];
#pragma unroll
        for (int k = 0; k < 8; ++k) acc[k] = fmaf(xv[k], wv[k], acc[k]);
    }
    zE[b * 768 + g * 256 + j] = ((acc[0] + acc[1]) + (acc[2] + acc[3]))
                              + ((acc[4] + acc[5]) + (acc[6] + acc[7]));
}

// ---- tail: gates + gamma + ntmout + conv2 -> A3 NHWC bf16 (block = image) ----
__global__ __launch_bounds__(1024) void tail_kernel(
    const float* __restrict__ zE, const float* __restrict__ bl,
    const float* __restrict__ gwT, const float* __restrict__ b_param,
    const float* __restrict__ w_out, const float* __restrict__ b_out,
    const double* __restrict__ rsP, const float* __restrict__ w2,
    const float* __restrict__ b2, unsigned short* __restrict__ ohi)
{
    int b = blockIdx.x, t = threadIdx.x;
    __shared__ float  sh[256];
    __shared__ double red[3][256];
    __shared__ double srv[3];
    __shared__ float  dP[4][256];
    __shared__ float  sNtm[256];

    if (t < 256) {                                     // gates (fp64 math)
        int j = t;
        float zif = (float)((double)zE[b * 768 + j]       + (double)bl[j]);
        float zgf = (float)((double)zE[b * 768 + 256 + j] + (double)bl[512 + j]);
        float zof = (float)((double)zE[b * 768 + 512 + j] + (double)bl[768 + j]);
        double c = (1.0 / (1.0 + exp(-(double)zif))) * tanh((double)zgf);
        float cf = (float)c;
        double hh = (1.0 / (1.0 + exp(-(double)zof))) * tanh((double)cf);
        sh[j] = (float)hh;
    }
    __syncthreads();
    // gamma: products (contiguous gwT) then LDS tree reduce
    if (t < 768) {
        int r = t >> 8, j = t & 255;
        red[r][j] = (double)sh[j] * (double)gwT[r * 256 + j];
    }
    __syncthreads();
    for (int s = 128; s > 0; s >>= 1) {
        if (t < 768) {
            int r = t >> 8, j = t & 255;
            if (j < s) red[r][j] += red[r][j + s];
        }
        __syncthreads();
    }
    if (t < 3) {
        double s = red[t][0];
        float pf = (float)(s + (double)b_param[t * 262 + 261]);
        pf = fminf(fmaxf(pf, -20.f), 20.f);
        double gamma = log1p(exp((double)pf)) + 1.0;
        double q = pow(0.015625 + 1e-16, gamma);
        double wv = q / (64.0 * q + 1e-8);
        srv[t] = wv * 64.0 * 1e-6;
    }
    __syncthreads();
    // ntmout dot: thread (q, m), quarter-dots of 64 terms, 4-acc fp32
    {
        int q = t >> 8, m = t & 255;
        const float* wp = w_out + (size_t)(q * 64) * 256 + m;
        float a4[4] = {0.f, 0.f, 0.f, 0.f};
        for (int d0 = 0; d0 < 64; d0 += 4) {
            float hv4[4], wv4[4];
#pragma unroll
            for (int k = 0; k < 4; ++k) hv4[k] = sh[q * 64 + d0 + k];
#pragma unroll
            for (int k = 0; k < 4; ++k) wv4[k] = wp[(size_t)(d0 + k) * 256];
#pragma unroll
            for (int k = 0; k < 4; ++k) a4[k] = fmaf(hv4[k], wv4[k], a4[k]);
        }
        dP[q][m] = (a4[0] + a4[1]) + (a4[2] + a4[3]);
    }
    __syncthreads();
    if (t < 256) {
        int m = t;
        float dotf = (dP[0][m] + dP[1][m]) + (dP[2][m] + dP[3][m]);
        double acc = (double)dotf + (double)b_out[m];
#pragma unroll
        for (int r = 0; r < 3; ++r) {
            double rsum = 0;
#pragma unroll
            for (int c = 0; c < 8; ++c) rsum += rsP[((r * 8 + c) << 8) + m];
            acc += srv[r] * rsum;
        }
        acc = fmin(fmax(acc, -20.0), 20.0);
        sNtm[m] = (float)acc;
    }
    __syncthreads();
    // conv2: 1->64 3x3 SAME + relu -> A3 NHWC bf16
    for (int p = t; p < 16384; p += 1024) {
        int co = p & 63, x4 = (p >> 6) & 15, y4 = p >> 10;
        float a = b2[co];
#pragma unroll
        for (int ky = 0; ky < 3; ++ky) {
            int gy = y4 + ky - 1;
            if ((unsigned)gy >= 16u) continue;
#pragma unroll
            for (int kx = 0; kx < 3; ++kx) {
                int gx = x4 + kx - 1;
                if ((unsigned)gx >= 16u) continue;
                a = fmaf(w2[co * 9 + ky * 3 + kx], sNtm[gy * 16 + gx], a);
            }
        }
        size_t adst = ((size_t)(b * 18 + y4 + 1) * 18 + x4 + 1) * 64 + co;
        ohi[adst] = bf16of(fmaxf(a, 0.f));
    }
}

extern "C" void kernel_launch(void* const* d_in, const int* in_sizes, int n_in,
                              void* d_out, int out_size, void* d_ws, size_t ws_size,
                              hipStream_t stream)
{
    const float* inputs   = (const float*)d_in[0];
    const float* w_conv0  = (const float*)d_in[1];
    const float* b_conv0  = (const float*)d_in[2];
    const float* w_conv1  = (const float*)d_in[3];
    const float* b_conv1  = (const float*)d_in[4];
    const float* w_enc    = (const float*)d_in[5];
    const float* b_enc    = (const float*)d_in[6];
    const float* w_conv2  = (const float*)d_in[7];
    const float* b_conv2  = (const float*)d_in[8];
    const float* w_conv3  = (const float*)d_in[9];
    const float* b_conv3  = (const float*)d_in[10];
    const float* w_conv4  = (const float*)d_in[11];
    const float* b_conv4  = (const float*)d_in[12];
    const float* w_lstm_x = (const float*)d_in[13];
    // d_in[14] = w_lstm_h : dead (h0 == 0)
    const float* b_lstm   = (const float*)d_in[15];
    const float* w_param  = (const float*)d_in[16];
    const float* b_param  = (const float*)d_in[17];
    const float* w_out_   = (const float*)d_in[18];
    const float* b_out_   = (const float*)d_in[19];

    char* ws = (char*)d_ws;
    unsigned short* a1h = (unsigned short*)(ws + OFF_A1H);
    float*  pooled = (float*)(ws + OFF_PL);
    unsigned short* a3h = (unsigned short*)(ws + OFF_A3H);
    unsigned short* a4h = a1h;                         // A4 reuses A1
    unsigned short* whi1 = (unsigned short*)(ws + OFF_W1); unsigned short* wlo1 = whi1 + 36864;
    unsigned short* whi3 = (unsigned short*)(ws + OFF_W3); unsigned short* wlo3 = whi3 + 36864;
    unsigned short* whi4 = (unsigned short*)(ws + OFF_W4); unsigned short* wlo4 = whi4 + 36864;
    double* rsP = (double*)(ws + OFF_RS);
    float*  xE  = (float*)(ws + OFF_XE);
    float*  zE  = (float*)(ws + OFF_Z);
    float*  gwT = (float*)(ws + OFF_GW);

    wprep_rowsum_kernel<<<457, 256, 0, stream>>>(
        w_conv1, w_conv3, w_conv4, w_out_, w_param,
        whi1, wlo1, whi3, wlo3, whi4, wlo4, rsP, gwT);
    halo_all_kernel<<<3200, 256, 0, stream>>>(a1h, a3h);

    conv0_pool_kernel<<<16384, 256, 0, stream>>>(inputs, w_conv0, b_conv0, a1h);
    conv1_mfma_kernel<<<512, 256, 0, stream>>>(a1h, whi1, wlo1, b_conv1, pooled);

    enc_kernel<<<64, 1024, 0, stream>>>(pooled, w_enc, b_enc, xE);
    lstm_kernel<<<192, 256, 0, stream>>>(xE, w_lstm_x, zE);
    tail_kernel<<<64, 1024, 0, stream>>>(
        zE, b_lstm, gwT, b_param, w_out_, b_out_, rsP, w_conv2, b_conv2, a3h);

    conv3_mfma_kernel<<<512, 256, 0, stream>>>(a3h, whi3, wlo3, b_conv3, a4h);
    conv4_mfma_kernel<<<1024, 256, 0, stream>>>(a4h, whi4, wlo4, b_conv4, (float*)d_out);
}